// Round 5
// baseline (377.508 us; speedup 1.0000x reference)
//
#include <hip/hip_runtime.h>

// R5: fix GEMM latency-boundness (R4: qkv/outln ~114 µs each, occupancy 15%,
// MfmaUtil 10%). qkv: m-dim (Q/K/V) split across grid -> 3x blocks; outln:
// 64 rows/block -> 2x blocks, fewer VGPRs. attn unchanged (BW-bound at
// ~3.65 TB/s gather, matched prediction).

typedef short bf16x8 __attribute__((ext_vector_type(8)));
typedef float f32x4  __attribute__((ext_vector_type(4)));

__device__ __forceinline__ ushort f2bf(float f) {   // RTN-even
    uint u = __builtin_bit_cast(uint, f);
    u += 0x7fffu + ((u >> 16) & 1u);
    return (ushort)(u >> 16);
}
__device__ __forceinline__ float bf2f(ushort b) {
    uint u = ((uint)b) << 16;
    return __builtin_bit_cast(float, u);
}

// ---------------------------------------------------------------------------
// prep: split Wq,Wk,Wv,Wo (fp32 [128][128]) into hi/lo bf16.
// Whl: mat m at m*32768: [0,16384)=hi, [16384,32768)=lo.
// ---------------------------------------------------------------------------
__global__ __launch_bounds__(256) void prep_kernel(
    const float* __restrict__ Wq, const float* __restrict__ Wk,
    const float* __restrict__ Wv, const float* __restrict__ Wo,
    ushort* __restrict__ Whl)
{
    int e = blockIdx.x * 256 + threadIdx.x;        // 0..65535
    const float* W[4] = {Wq, Wk, Wv, Wo};
    int m = e >> 14, i = e & 16383;
    float x = W[m][i];
    ushort hi = f2bf(x);
    ushort lo = f2bf(x - bf2f(hi));
    Whl[m * 32768 + i] = hi;
    Whl[m * 32768 + 16384 + i] = lo;
}

// ---------------------------------------------------------------------------
// qkv: one (row-block, mat) pair per block.  mat 0 -> Qb, 1 -> K half of KVb,
// 2 -> V half.  Wave owns 32 rows x 128 cols; bf16x3 split MFMAs.
// ---------------------------------------------------------------------------
__global__ __launch_bounds__(256) void qkv_kernel(
    const float* __restrict__ h, const ushort* __restrict__ Whl,
    ushort* __restrict__ Qb, ushort* __restrict__ KVb, int N)
{
    const int m    = blockIdx.x % 3;
    const int rb   = blockIdx.x / 3;
    const int wave = threadIdx.x >> 6;
    const int lane = threadIdx.x & 63;
    const int lg = lane >> 4;        // k-group 0..3
    const int lr = lane & 15;        // A row / B col within tile
    const int r0 = rb * 128 + wave * 32;

    // load + split A fragments
    bf16x8 ahi[2][4], alo[2][4];
    #pragma unroll
    for (int rt = 0; rt < 2; ++rt) {
        int row = r0 + rt * 16 + lr;
        bool ok = row < N;
        const float* hp = h + (size_t)row * 128 + lg * 8;
        #pragma unroll
        for (int k0 = 0; k0 < 4; ++k0) {
            float4 x0 = make_float4(0.f, 0.f, 0.f, 0.f), x1 = x0;
            if (ok) {
                x0 = *(const float4*)(hp + k0 * 32);
                x1 = *(const float4*)(hp + k0 * 32 + 4);
            }
            float xs[8] = {x0.x, x0.y, x0.z, x0.w, x1.x, x1.y, x1.z, x1.w};
            bf16x8 H, L;
            #pragma unroll
            for (int i = 0; i < 8; ++i) {
                ushort hb = f2bf(xs[i]);
                H[i] = (short)hb;
                L[i] = (short)f2bf(xs[i] - bf2f(hb));
            }
            ahi[rt][k0] = H; alo[rt][k0] = L;
        }
    }

    const ushort* Whi = Whl + m * 32768;
    const ushort* Wlo = Whi + 16384;
    f32x4 acc[2][8];
    #pragma unroll
    for (int rt = 0; rt < 2; ++rt)
        #pragma unroll
        for (int n = 0; n < 8; ++n)
            acc[rt][n] = f32x4{0.f, 0.f, 0.f, 0.f};

    #pragma unroll
    for (int n = 0; n < 8; ++n) {
        size_t boff = (size_t)(n * 16 + lr) * 128 + lg * 8;
        #pragma unroll
        for (int k0 = 0; k0 < 4; ++k0) {
            bf16x8 bh = *(const bf16x8*)(Whi + boff + k0 * 32);
            bf16x8 bl = *(const bf16x8*)(Wlo + boff + k0 * 32);
            #pragma unroll
            for (int rt = 0; rt < 2; ++rt) {
                acc[rt][n] = __builtin_amdgcn_mfma_f32_16x16x32_bf16(ahi[rt][k0], bh, acc[rt][n], 0, 0, 0);
                acc[rt][n] = __builtin_amdgcn_mfma_f32_16x16x32_bf16(ahi[rt][k0], bl, acc[rt][n], 0, 0, 0);
                acc[rt][n] = __builtin_amdgcn_mfma_f32_16x16x32_bf16(alo[rt][k0], bh, acc[rt][n], 0, 0, 0);
            }
        }
    }

    // C/D layout: col = lane&15, row = (lane>>4)*4 + reg
    const int vhalf = (m == 1) ? 0 : 128;          // used when m != 0
    #pragma unroll
    for (int rt = 0; rt < 2; ++rt)
        #pragma unroll
        for (int reg = 0; reg < 4; ++reg) {
            int row = r0 + rt * 16 + lg * 4 + reg;
            if (row < N) {
                #pragma unroll
                for (int n = 0; n < 8; ++n) {
                    int col = n * 16 + lr;
                    ushort v = f2bf(acc[rt][n][reg]);
                    if (m == 0) Qb [(size_t)row * 128 + col] = v;
                    else        KVb[(size_t)row * 256 + vhalf + col] = v;
                }
            }
        }
}

// ---------------------------------------------------------------------------
// attn: one wave per node; lane owns dims (2l,2l+1); head = 8-lane group.
// KV row: bytes [0,256) = K, [256,512) = V.  Ab aliases Qb.
// ---------------------------------------------------------------------------
__global__ __launch_bounds__(256) void attn_kernel(
    const ushort* Qb, const ushort* __restrict__ KVb,
    const int* __restrict__ nbr, ushort* Ab, int N)
{
    int gid = blockIdx.x * blockDim.x + threadIdx.x;
    int n = gid >> 6;
    int lane = threadIdx.x & 63;
    if (n >= N) return;

    uint qw = *(const uint*)(Qb + (size_t)n * 128 + 2 * lane);
    float qx = bf2f((ushort)(qw & 0xffffu));
    float qy = bf2f((ushort)(qw >> 16));

    int idx[16];
    #pragma unroll
    for (int j = 0; j < 16; ++j) idx[j] = nbr[n * 16 + j];

    float logit[16];
    #pragma unroll
    for (int j = 0; j < 16; ++j) {
        uint kw = *(const uint*)(KVb + (size_t)idx[j] * 256 + 2 * lane);
        float s = qx * bf2f((ushort)(kw & 0xffffu))
                + qy * bf2f((ushort)(kw >> 16));
        s += __shfl_xor(s, 1);
        s += __shfl_xor(s, 2);
        s += __shfl_xor(s, 4);
        logit[j] = s * 0.25f;                       // D^-0.5
    }

    float m = logit[0];
    #pragma unroll
    for (int j = 1; j < 16; ++j) m = fmaxf(m, logit[j]);
    float sum = 0.f;
    #pragma unroll
    for (int j = 0; j < 16; ++j) { logit[j] = __expf(logit[j] - m); sum += logit[j]; }
    float inv = 1.f / sum;

    float ax = 0.f, ay = 0.f;
    #pragma unroll
    for (int j = 0; j < 16; ++j) {
        uint vw = *(const uint*)(KVb + (size_t)idx[j] * 256 + 128 + 2 * lane);
        float p = logit[j] * inv;
        ax += p * bf2f((ushort)(vw & 0xffffu));
        ay += p * bf2f((ushort)(vw >> 16));
    }
    uint out = (uint)f2bf(ax) | ((uint)f2bf(ay) << 16);
    *(uint*)(Ab + (size_t)n * 128 + 2 * lane) = out;
}

// ---------------------------------------------------------------------------
// outln: out = LN(h + A@Wo^T + bo)*gamma + beta.  64 rows/block (wave owns
// 16 rows).  A exact bf16 -> 2 MFMAs/tile.
// ---------------------------------------------------------------------------
__global__ __launch_bounds__(256) void outln_kernel(
    const ushort* __restrict__ Ab, const ushort* __restrict__ Whl,
    const float* __restrict__ bo, const float* __restrict__ h,
    const float* __restrict__ gamma, const float* __restrict__ beta,
    float* __restrict__ out, int N)
{
    const int wave = threadIdx.x >> 6;
    const int lane = threadIdx.x & 63;
    const int lg = lane >> 4;
    const int lr = lane & 15;
    const int r0 = blockIdx.x * 64 + wave * 16;

    bf16x8 af[4];
    {
        int row = r0 + lr;
        bool ok = row < N;
        const ushort* ap = Ab + (size_t)row * 128 + lg * 8;
        #pragma unroll
        for (int k0 = 0; k0 < 4; ++k0) {
            bf16x8 a = bf16x8{0,0,0,0,0,0,0,0};
            if (ok) a = *(const bf16x8*)(ap + k0 * 32);
            af[k0] = a;
        }
    }

    const ushort* Whi = Whl + 3 * 32768;
    const ushort* Wlo = Whi + 16384;
    f32x4 acc[8];
    #pragma unroll
    for (int n = 0; n < 8; ++n) acc[n] = f32x4{0.f, 0.f, 0.f, 0.f};

    #pragma unroll
    for (int n = 0; n < 8; ++n) {
        size_t boff = (size_t)(n * 16 + lr) * 128 + lg * 8;
        #pragma unroll
        for (int k0 = 0; k0 < 4; ++k0) {
            bf16x8 bh = *(const bf16x8*)(Whi + boff + k0 * 32);
            bf16x8 bl = *(const bf16x8*)(Wlo + boff + k0 * 32);
            acc[n] = __builtin_amdgcn_mfma_f32_16x16x32_bf16(af[k0], bh, acc[n], 0, 0, 0);
            acc[n] = __builtin_amdgcn_mfma_f32_16x16x32_bf16(af[k0], bl, acc[n], 0, 0, 0);
        }
    }

    float bo_r[8], g_r[8], b_r[8];
    #pragma unroll
    for (int n = 0; n < 8; ++n) {
        int col = n * 16 + lr;
        bo_r[n] = bo[col]; g_r[n] = gamma[col]; b_r[n] = beta[col];
    }

    float s[4] = {0.f, 0.f, 0.f, 0.f}, s2[4] = {0.f, 0.f, 0.f, 0.f};
    #pragma unroll
    for (int reg = 0; reg < 4; ++reg) {
        int row = r0 + lg * 4 + reg;
        bool ok = row < N;
        const float* hrow = h + (size_t)row * 128;
        #pragma unroll
        for (int n = 0; n < 8; ++n) {
            int col = n * 16 + lr;
            float xx = acc[n][reg] + bo_r[n] + (ok ? hrow[col] : 0.f);
            acc[n][reg] = xx;
            s[reg] += xx;
            s2[reg] += xx * xx;
        }
    }
    #pragma unroll
    for (int reg = 0; reg < 4; ++reg) {
        float a = s[reg], b2 = s2[reg];
        #pragma unroll
        for (int d = 1; d < 16; d <<= 1) {
            a  += __shfl_xor(a,  d);
            b2 += __shfl_xor(b2, d);
        }
        float mu  = a * (1.f / 128.f);
        float var = b2 * (1.f / 128.f) - mu * mu;
        float rstd = rsqrtf(var + 1e-5f);
        int row = r0 + lg * 4 + reg;
        if (row < N) {
            #pragma unroll
            for (int n = 0; n < 8; ++n) {
                int col = n * 16 + lr;
                out[(size_t)row * 128 + col] =
                    (acc[n][reg] - mu) * rstd * g_r[n] + b_r[n];
            }
        }
    }
}

extern "C" void kernel_launch(void* const* d_in, const int* in_sizes, int n_in,
                              void* d_out, int out_size, void* d_ws, size_t ws_size,
                              hipStream_t stream) {
    const float* h   = (const float*)d_in[0];
    const int*   nbr = (const int*)  d_in[1];
    const float* Wq  = (const float*)d_in[2];
    const float* Wk  = (const float*)d_in[3];
    const float* Wv  = (const float*)d_in[4];
    const float* Wo  = (const float*)d_in[5];
    const float* bo  = (const float*)d_in[6];
    const float* gam = (const float*)d_in[7];
    const float* bet = (const float*)d_in[8];

    const int N = in_sizes[0] / 128;

    // ws: Qb bf16 N*128 | KVb bf16 N*256 | Whl bf16 4*32768.  Ab aliases Qb.
    ushort* Qb  = (ushort*)d_ws;
    ushort* KVb = Qb + (size_t)N * 128;
    ushort* Whl = KVb + (size_t)N * 256;
    ushort* Ab  = Qb;
    float*  out = (float*)d_out;

    prep_kernel<<<256, 256, 0, stream>>>(Wq, Wk, Wv, Wo, Whl);
    const int nbRow = (N + 127) / 128;
    qkv_kernel<<<nbRow * 3, 256, 0, stream>>>(h, Whl, Qb, KVb, N);
    attn_kernel<<<(N + 3) / 4, 256, 0, stream>>>(Qb, KVb, nbr, Ab, N);
    outln_kernel<<<(N + 63) / 64, 256, 0, stream>>>(Ab, Whl, bo, h, gam, bet, out, N);
}

// Round 9
// 295.078 us; speedup vs baseline: 1.2794x; 1.2794x over previous
//
#include <hip/hip_runtime.h>

// R6 resubmit x3 (R6/R7/R8 benches never acquired a GPU). GEMMs restructured:
// weights staged once per block into LDS with XOR swizzle (conflict-free
// ds_read_b128); MFMA operands SWAPPED (A=W, B=h) so each thread owns 4
// consecutive output cols of one row -> packed ushort4 / float4 stores and a
// 2-shuffle LN reduce. Numerics identical to R5 (x3 split qkv, x2 outln):
// absmax must stay 0.03125. attn unchanged (isolation).

typedef short  bf16x8 __attribute__((ext_vector_type(8)));
typedef float  f32x4  __attribute__((ext_vector_type(4)));
typedef ushort u16x4  __attribute__((ext_vector_type(4)));

// swizzle a byte offset within a [row][256B] LDS image: spread the 16B slot
// across banks by XORing with (row&7)<<4. Bijective per row; 16B-aligned.
#define SWZ(b) ((b) ^ ((((b) >> 8) & 7) << 4))

__device__ __forceinline__ ushort f2bf(float f) {   // RTN-even
    uint u = __builtin_bit_cast(uint, f);
    u += 0x7fffu + ((u >> 16) & 1u);
    return (ushort)(u >> 16);
}
__device__ __forceinline__ float bf2f(ushort b) {
    uint u = ((uint)b) << 16;
    return __builtin_bit_cast(float, u);
}

// ---------------------------------------------------------------------------
// prep: split Wq,Wk,Wv,Wo (fp32 [128][128]) into hi/lo bf16.
// Whl: mat m at m*32768 ushorts: [0,16384)=hi, [16384,32768)=lo.
// ---------------------------------------------------------------------------
__global__ __launch_bounds__(256) void prep_kernel(
    const float* __restrict__ Wq, const float* __restrict__ Wk,
    const float* __restrict__ Wv, const float* __restrict__ Wo,
    ushort* __restrict__ Whl)
{
    int e = blockIdx.x * 256 + threadIdx.x;        // 0..65535
    const float* W[4] = {Wq, Wk, Wv, Wo};
    int m = e >> 14, i = e & 16383;
    float x = W[m][i];
    ushort hi = f2bf(x);
    ushort lo = f2bf(x - bf2f(hi));
    Whl[m * 32768 + i] = hi;
    Whl[m * 32768 + 16384 + i] = lo;
}

// ---------------------------------------------------------------------------
// qkv: block = (row-block, mat m).  Stage m's 64KB hi+lo weight table into
// swizzled LDS once; wave owns 32 rows; per (n,k0): 2 ds_read_b128 W-frags,
// 3 MFMAs x 2 row-tiles (x3 split).  Packed ushort4 stores.
// ---------------------------------------------------------------------------
__global__ __launch_bounds__(256) void qkv_kernel(
    const float* __restrict__ h, const ushort* __restrict__ Whl,
    ushort* __restrict__ Qb, ushort* __restrict__ KVb, int N)
{
    __shared__ ushort wlds[32768];                 // 64 KB swizzled hi+lo
    const int t    = threadIdx.x;
    const int m    = blockIdx.x % 3;
    const int rb   = blockIdx.x / 3;
    const int wave = t >> 6;
    const int lane = t & 63;
    const int lg   = lane >> 4;                    // k-subgroup 0..3
    const int lr   = lane & 15;                    // row/col slot 0..15
    const int r0   = rb * 128 + wave * 32;

    // ---- stage weights: 16 iters x 256 thr x 16B = 64KB, swizzled ----
    const ushort* Wsrc = Whl + m * 32768;
    #pragma unroll
    for (int i = 0; i < 16; ++i) {
        int e = (i * 256 + t) * 8;                 // ushort index
        uint4 d = *(const uint4*)(Wsrc + e);
        int b = e * 2;                             // byte offset
        *(uint4*)((char*)wlds + SWZ(b)) = d;
    }

    // ---- h B-frags hi/lo (rt in {0,1}, k0 in {0..3}) ----
    bf16x8 bhi[2][4], blo[2][4];
    #pragma unroll
    for (int rt = 0; rt < 2; ++rt) {
        int row = r0 + rt * 16 + lr;
        bool ok = row < N;
        const float* hp = h + (size_t)row * 128 + lg * 8;
        #pragma unroll
        for (int k0 = 0; k0 < 4; ++k0) {
            float4 x0 = make_float4(0.f, 0.f, 0.f, 0.f), x1 = x0;
            if (ok) {
                x0 = *(const float4*)(hp + k0 * 32);
                x1 = *(const float4*)(hp + k0 * 32 + 4);
            }
            float xs[8] = {x0.x, x0.y, x0.z, x0.w, x1.x, x1.y, x1.z, x1.w};
            bf16x8 H, L;
            #pragma unroll
            for (int i = 0; i < 8; ++i) {
                ushort hb = f2bf(xs[i]);
                H[i] = (short)hb;
                L[i] = (short)f2bf(xs[i] - bf2f(hb));
            }
            bhi[rt][k0] = H; blo[rt][k0] = L;
        }
    }

    __syncthreads();

    f32x4 acc[2][8];
    #pragma unroll
    for (int rt = 0; rt < 2; ++rt)
        #pragma unroll
        for (int n = 0; n < 8; ++n)
            acc[rt][n] = f32x4{0.f, 0.f, 0.f, 0.f};

    #pragma unroll
    for (int n = 0; n < 8; ++n) {
        #pragma unroll
        for (int k0 = 0; k0 < 4; ++k0) {
            int wb = (n * 16 + lr) * 256 + k0 * 64 + lg * 16;   // hi byte off
            bf16x8 wh = *(const bf16x8*)((const char*)wlds + SWZ(wb));
            bf16x8 wl = *(const bf16x8*)((const char*)wlds + SWZ(wb + 32768));
            #pragma unroll
            for (int rt = 0; rt < 2; ++rt) {
                acc[rt][n] = __builtin_amdgcn_mfma_f32_16x16x32_bf16(wh, bhi[rt][k0], acc[rt][n], 0, 0, 0);
                acc[rt][n] = __builtin_amdgcn_mfma_f32_16x16x32_bf16(wh, blo[rt][k0], acc[rt][n], 0, 0, 0);
                acc[rt][n] = __builtin_amdgcn_mfma_f32_16x16x32_bf16(wl, bhi[rt][k0], acc[rt][n], 0, 0, 0);
            }
        }
    }

    // swapped layout: out-row = r0+rt*16+lr, out-cols = n*16+lg*4 + 0..3
    const int vhalf = (m == 1) ? 0 : 128;
    #pragma unroll
    for (int rt = 0; rt < 2; ++rt) {
        int row = r0 + rt * 16 + lr;
        if (row < N) {
            #pragma unroll
            for (int n = 0; n < 8; ++n) {
                u16x4 pv;
                #pragma unroll
                for (int j = 0; j < 4; ++j) pv[j] = f2bf(acc[rt][n][j]);
                int col = n * 16 + lg * 4;
                if (m == 0) *(u16x4*)(Qb  + (size_t)row * 128 + col) = pv;
                else        *(u16x4*)(KVb + (size_t)row * 256 + vhalf + col) = pv;
            }
        }
    }
}

// ---------------------------------------------------------------------------
// attn: one wave per node (unchanged from R5 — BW-bound control).
// ---------------------------------------------------------------------------
__global__ __launch_bounds__(256) void attn_kernel(
    const ushort* Qb, const ushort* __restrict__ KVb,
    const int* __restrict__ nbr, ushort* Ab, int N)
{
    int gid = blockIdx.x * blockDim.x + threadIdx.x;
    int n = gid >> 6;
    int lane = threadIdx.x & 63;
    if (n >= N) return;

    uint qw = *(const uint*)(Qb + (size_t)n * 128 + 2 * lane);
    float qx = bf2f((ushort)(qw & 0xffffu));
    float qy = bf2f((ushort)(qw >> 16));

    int idx[16];
    #pragma unroll
    for (int j = 0; j < 16; ++j) idx[j] = nbr[n * 16 + j];

    float logit[16];
    #pragma unroll
    for (int j = 0; j < 16; ++j) {
        uint kw = *(const uint*)(KVb + (size_t)idx[j] * 256 + 2 * lane);
        float s = qx * bf2f((ushort)(kw & 0xffffu))
                + qy * bf2f((ushort)(kw >> 16));
        s += __shfl_xor(s, 1);
        s += __shfl_xor(s, 2);
        s += __shfl_xor(s, 4);
        logit[j] = s * 0.25f;                       // D^-0.5
    }

    float m = logit[0];
    #pragma unroll
    for (int j = 1; j < 16; ++j) m = fmaxf(m, logit[j]);
    float sum = 0.f;
    #pragma unroll
    for (int j = 0; j < 16; ++j) { logit[j] = __expf(logit[j] - m); sum += logit[j]; }
    float inv = 1.f / sum;

    float ax = 0.f, ay = 0.f;
    #pragma unroll
    for (int j = 0; j < 16; ++j) {
        uint vw = *(const uint*)(KVb + (size_t)idx[j] * 256 + 128 + 2 * lane);
        float p = logit[j] * inv;
        ax += p * bf2f((ushort)(vw & 0xffffu));
        ay += p * bf2f((ushort)(vw >> 16));
    }
    uint out = (uint)f2bf(ax) | ((uint)f2bf(ay) << 16);
    *(uint*)(Ab + (size_t)n * 128 + 2 * lane) = out;
}

// ---------------------------------------------------------------------------
// outln: out = LN(h + A@Wo^T + bo)*gamma + beta.  64 rows/block (wave = 16
// rows, lane lr owns row lr).  Wo staged swizzled in LDS; A exact bf16 ->
// 2 MFMAs per (n,k0).  Swapped layout: thread holds cols n*16+lg*4..+3 of
// its row -> float4 epilogue, LN reduce = 2 shuffles (xor 16, 32).
// ---------------------------------------------------------------------------
__global__ __launch_bounds__(256) void outln_kernel(
    const ushort* __restrict__ Ab, const ushort* __restrict__ Whl,
    const float* __restrict__ bo, const float* __restrict__ h,
    const float* __restrict__ gamma, const float* __restrict__ beta,
    float* __restrict__ out, int N)
{
    __shared__ ushort wlds[32768];                 // 64 KB swizzled Wo hi+lo
    const int t    = threadIdx.x;
    const int wave = t >> 6;
    const int lane = t & 63;
    const int lg   = lane >> 4;
    const int lr   = lane & 15;
    const int r0   = blockIdx.x * 64 + wave * 16;
    const int row  = r0 + lr;
    const bool ok  = row < N;

    const ushort* Wsrc = Whl + 3 * 32768;
    #pragma unroll
    for (int i = 0; i < 16; ++i) {
        int e = (i * 256 + t) * 8;
        uint4 d = *(const uint4*)(Wsrc + e);
        int b = e * 2;
        *(uint4*)((char*)wlds + SWZ(b)) = d;
    }

    // A B-frags (exact bf16)
    bf16x8 af[4];
    {
        const ushort* ap = Ab + (size_t)row * 128 + lg * 8;
        #pragma unroll
        for (int k0 = 0; k0 < 4; ++k0) {
            bf16x8 a = bf16x8{0,0,0,0,0,0,0,0};
            if (ok) a = *(const bf16x8*)(ap + k0 * 32);
            af[k0] = a;
        }
    }

    __syncthreads();

    f32x4 acc[8];
    #pragma unroll
    for (int n = 0; n < 8; ++n) acc[n] = f32x4{0.f, 0.f, 0.f, 0.f};

    #pragma unroll
    for (int n = 0; n < 8; ++n) {
        #pragma unroll
        for (int k0 = 0; k0 < 4; ++k0) {
            int wb = (n * 16 + lr) * 256 + k0 * 64 + lg * 16;
            bf16x8 wh = *(const bf16x8*)((const char*)wlds + SWZ(wb));
            bf16x8 wl = *(const bf16x8*)((const char*)wlds + SWZ(wb + 32768));
            acc[n] = __builtin_amdgcn_mfma_f32_16x16x32_bf16(wh, af[k0], acc[n], 0, 0, 0);
            acc[n] = __builtin_amdgcn_mfma_f32_16x16x32_bf16(wl, af[k0], acc[n], 0, 0, 0);
        }
    }

    // epilogue: bias + residual, row stats over 32 in-thread + 2 shuffles
    float s = 0.f, s2 = 0.f;
    const float* hrow = h + (size_t)row * 128;
    #pragma unroll
    for (int n = 0; n < 8; ++n) {
        int col = n * 16 + lg * 4;
        f32x4 hres = f32x4{0.f, 0.f, 0.f, 0.f};
        if (ok) hres = *(const f32x4*)(hrow + col);
        f32x4 bov = *(const f32x4*)(bo + col);
        #pragma unroll
        for (int j = 0; j < 4; ++j) {
            float xx = acc[n][j] + bov[j] + hres[j];
            acc[n][j] = xx;
            s += xx;
            s2 += xx * xx;
        }
    }
    s  += __shfl_xor(s, 16);  s  += __shfl_xor(s, 32);
    s2 += __shfl_xor(s2, 16); s2 += __shfl_xor(s2, 32);

    float mu   = s * (1.f / 128.f);
    float var  = s2 * (1.f / 128.f) - mu * mu;
    float rstd = rsqrtf(var + 1e-5f);

    if (ok) {
        #pragma unroll
        for (int n = 0; n < 8; ++n) {
            int col = n * 16 + lg * 4;
            f32x4 g  = *(const f32x4*)(gamma + col);
            f32x4 be = *(const f32x4*)(beta + col);
            f32x4 o;
            #pragma unroll
            for (int j = 0; j < 4; ++j)
                o[j] = (acc[n][j] - mu) * rstd * g[j] + be[j];
            *(f32x4*)(out + (size_t)row * 128 + col) = o;
        }
    }
}

extern "C" void kernel_launch(void* const* d_in, const int* in_sizes, int n_in,
                              void* d_out, int out_size, void* d_ws, size_t ws_size,
                              hipStream_t stream) {
    const float* h   = (const float*)d_in[0];
    const int*   nbr = (const int*)  d_in[1];
    const float* Wq  = (const float*)d_in[2];
    const float* Wk  = (const float*)d_in[3];
    const float* Wv  = (const float*)d_in[4];
    const float* Wo  = (const float*)d_in[5];
    const float* bo  = (const float*)d_in[6];
    const float* gam = (const float*)d_in[7];
    const float* bet = (const float*)d_in[8];

    const int N = in_sizes[0] / 128;

    // ws: Qb bf16 N*128 | KVb bf16 N*256 | Whl bf16 4*32768.  Ab aliases Qb.
    ushort* Qb  = (ushort*)d_ws;
    ushort* KVb = Qb + (size_t)N * 128;
    ushort* Whl = KVb + (size_t)N * 256;
    ushort* Ab  = Qb;
    float*  out = (float*)d_out;

    prep_kernel<<<256, 256, 0, stream>>>(Wq, Wk, Wv, Wo, Whl);
    const int nbRow = (N + 127) / 128;
    qkv_kernel<<<nbRow * 3, 256, 0, stream>>>(h, Whl, Qb, KVb, N);
    attn_kernel<<<(N + 3) / 4, 256, 0, stream>>>(Qb, KVb, nbr, Ab, N);
    outln_kernel<<<(N + 63) / 64, 256, 0, stream>>>(Ab, Whl, bo, h, gam, bet, out, N);
}